// Round 1
// baseline (526.538 us; speedup 1.0000x reference)
//
#include <hip/hip_runtime.h>
#include <math.h>

#define F_IN 128
#define F_HID 256
#define F_OUT 10

// ---------------- degree / CSR build ----------------

__global__ void count_kernel(const int* __restrict__ dst, int* __restrict__ cnt, int e) {
    int i = blockIdx.x * blockDim.x + threadIdx.x;
    if (i < e) atomicAdd(&cnt[dst[i]], 1);
}

__global__ void dinv_kernel(const int* __restrict__ cnt, float* __restrict__ dinv, int n) {
    int i = blockIdx.x * blockDim.x + threadIdx.x;
    if (i < n) dinv[i] = rsqrtf((float)(cnt[i] + 1));  // +1 self loop
}

__global__ void scan1_kernel(const int* __restrict__ cnt, int* __restrict__ rowstart,
                             int* __restrict__ partial, int n) {
    __shared__ int s[256];
    int tid = threadIdx.x;
    int i = blockIdx.x * 256 + tid;
    int v = (i < n) ? cnt[i] : 0;
    s[tid] = v;
    __syncthreads();
    for (int off = 1; off < 256; off <<= 1) {
        int t = (tid >= off) ? s[tid - off] : 0;
        __syncthreads();
        s[tid] += t;
        __syncthreads();
    }
    if (i < n) rowstart[i] = s[tid] - v;          // exclusive
    if (tid == 255) partial[blockIdx.x] = s[255]; // block total
}

__global__ void scan2_kernel(int* __restrict__ partial, int nb) {
    __shared__ int s[256];
    int tid = threadIdx.x;
    int v = (tid < nb) ? partial[tid] : 0;
    s[tid] = v;
    __syncthreads();
    for (int off = 1; off < 256; off <<= 1) {
        int t = (tid >= off) ? s[tid - off] : 0;
        __syncthreads();
        s[tid] += t;
        __syncthreads();
    }
    if (tid < nb) partial[tid] = s[tid] - v;      // exclusive block offsets
}

__global__ void scan3_kernel(int* __restrict__ rowstart, const int* __restrict__ partial,
                             int n, int e) {
    int i = blockIdx.x * blockDim.x + threadIdx.x;
    if (i < n) rowstart[i] += partial[blockIdx.x];
    if (i == 0) rowstart[n] = e;
}

__global__ void fill_kernel(const int* __restrict__ src, const int* __restrict__ dst,
                            const int* __restrict__ rowstart, int* __restrict__ cursor,
                            const float* __restrict__ dinv, int* __restrict__ csr_src,
                            float* __restrict__ csr_norm, int e) {
    int i = blockIdx.x * blockDim.x + threadIdx.x;
    if (i >= e) return;
    int s = src[i], d = dst[i];
    int pos = rowstart[d] + atomicAdd(&cursor[d], 1);
    csr_src[pos] = s;
    csr_norm[pos] = dinv[s] * dinv[d];
}

// ---------------- feature aggregation (block per node, thread per feature) ----------------

template <int F>
__global__ void agg_kernel(const float* __restrict__ feat, const int* __restrict__ rowstart,
                           const int* __restrict__ csr_src, const float* __restrict__ csr_norm,
                           const float* __restrict__ dinv, float* __restrict__ out, int n) {
    int v = blockIdx.x;
    int f = threadIdx.x;
    float d = dinv[v];
    float acc = d * d * feat[(size_t)v * F + f];  // self loop
    int e0 = rowstart[v], e1 = rowstart[v + 1];
    for (int e = e0; e < e1; ++e) {
        int s = csr_src[e];
        float w = csr_norm[e];
        acc += w * feat[(size_t)s * F + f];
    }
    out[(size_t)v * F + f] = acc;
}

// ---------------- fp32 tiled GEMM: C[M,N] = A[M,K] @ B[K,N] (+bias, relu) ----------------
// 64x64 tile per 256-thread block, 4x4 per thread, BK=16.

template <int K, bool RELU>
__global__ __launch_bounds__(256) void gemm_kernel(const float* __restrict__ A,
                                                   const float* __restrict__ B,
                                                   const float* __restrict__ bias,
                                                   float* __restrict__ C, int M, int N) {
    __shared__ float As[16][68];  // transposed: As[k][row], padded
    __shared__ float Bs[16][64];
    int tid = threadIdx.x;
    int tx = tid & 15, ty = tid >> 4;
    int arow = tid >> 2;
    int acol = (tid & 3) * 4;
    int brow = tid >> 4;
    int bcol = (tid & 15) * 4;
    int bm = blockIdx.x, bn = blockIdx.y;
    int grow = bm * 64 + arow;

    float acc[4][4] = {};

    for (int k0 = 0; k0 < K; k0 += 16) {
        float4 a4 = make_float4(0.f, 0.f, 0.f, 0.f);
        if (grow < M) a4 = *(const float4*)&A[(size_t)grow * K + k0 + acol];
        As[acol + 0][arow] = a4.x;
        As[acol + 1][arow] = a4.y;
        As[acol + 2][arow] = a4.z;
        As[acol + 3][arow] = a4.w;
        float4 b4 = *(const float4*)&B[(size_t)(k0 + brow) * N + bn * 64 + bcol];
        *(float4*)&Bs[brow][bcol] = b4;
        __syncthreads();
#pragma unroll
        for (int k = 0; k < 16; ++k) {
            float4 av = *(const float4*)&As[k][ty * 4];
            float4 bv = *(const float4*)&Bs[k][tx * 4];
            float a[4] = {av.x, av.y, av.z, av.w};
            float b[4] = {bv.x, bv.y, bv.z, bv.w};
#pragma unroll
            for (int i = 0; i < 4; ++i)
#pragma unroll
                for (int j = 0; j < 4; ++j) acc[i][j] += a[i] * b[j];
        }
        __syncthreads();
    }

    int row0 = bm * 64 + ty * 4;
    int col0 = bn * 64 + tx * 4;
#pragma unroll
    for (int i = 0; i < 4; ++i) {
        if (row0 + i >= M) break;
#pragma unroll
        for (int j = 0; j < 4; ++j) {
            float v = acc[i][j] + bias[col0 + j];
            if (RELU) v = fmaxf(v, 0.f);
            C[(size_t)(row0 + i) * N + col0 + j] = v;
        }
    }
}

// ---------------- small GEMM: hw3[M,10] = h[M,256] @ W3[256,10] ----------------

__global__ void gemm3_kernel(const float* __restrict__ h, const float* __restrict__ W3,
                             float* __restrict__ hw3, int M) {
    __shared__ float w[F_HID * F_OUT];
    for (int i = threadIdx.x; i < F_HID * F_OUT; i += blockDim.x) w[i] = W3[i];
    __syncthreads();
    int r = blockIdx.x * blockDim.x + threadIdx.x;
    if (r >= M) return;
    float acc[F_OUT] = {};
    const float* row = &h[(size_t)r * F_HID];
    for (int k = 0; k < F_HID; k += 4) {
        float4 hv = *(const float4*)&row[k];
#pragma unroll
        for (int j = 0; j < F_OUT; ++j) {
            acc[j] += hv.x * w[(k + 0) * F_OUT + j];
            acc[j] += hv.y * w[(k + 1) * F_OUT + j];
            acc[j] += hv.z * w[(k + 2) * F_OUT + j];
            acc[j] += hv.w * w[(k + 3) * F_OUT + j];
        }
    }
#pragma unroll
    for (int j = 0; j < F_OUT; ++j) hw3[(size_t)r * F_OUT + j] = acc[j];
}

// ---------------- final: 10-dim aggregation + bias + log_softmax ----------------

__global__ void final_kernel(const float* __restrict__ hw3, const int* __restrict__ rowstart,
                             const int* __restrict__ csr_src, const float* __restrict__ csr_norm,
                             const float* __restrict__ dinv, const float* __restrict__ b3,
                             float* __restrict__ out, int n) {
    int v = blockIdx.x * blockDim.x + threadIdx.x;
    if (v >= n) return;
    float acc[F_OUT];
    float d = dinv[v];
    float sw = d * d;
#pragma unroll
    for (int j = 0; j < F_OUT; ++j) acc[j] = sw * hw3[(size_t)v * F_OUT + j];
    int e0 = rowstart[v], e1 = rowstart[v + 1];
    for (int e = e0; e < e1; ++e) {
        int s = csr_src[e];
        float w = csr_norm[e];
#pragma unroll
        for (int j = 0; j < F_OUT; ++j) acc[j] += w * hw3[(size_t)s * F_OUT + j];
    }
#pragma unroll
    for (int j = 0; j < F_OUT; ++j) acc[j] += b3[j];
    float m = acc[0];
#pragma unroll
    for (int j = 1; j < F_OUT; ++j) m = fmaxf(m, acc[j]);
    float sum = 0.f;
#pragma unroll
    for (int j = 0; j < F_OUT; ++j) sum += expf(acc[j] - m);
    float lse = m + logf(sum);
#pragma unroll
    for (int j = 0; j < F_OUT; ++j) out[(size_t)v * F_OUT + j] = acc[j] - lse;
}

// ---------------- launch ----------------

extern "C" void kernel_launch(void* const* d_in, const int* in_sizes, int n_in,
                              void* d_out, int out_size, void* d_ws, size_t ws_size,
                              hipStream_t stream) {
    const float* x  = (const float*)d_in[0];
    const int*   ei = (const int*)d_in[1];
    const float* W1 = (const float*)d_in[2];
    const float* b1 = (const float*)d_in[3];
    const float* W2 = (const float*)d_in[4];
    const float* b2 = (const float*)d_in[5];
    const float* W3 = (const float*)d_in[6];
    const float* b3 = (const float*)d_in[7];
    float* out = (float*)d_out;

    int n = in_sizes[0] / F_IN;
    int e = in_sizes[1] / 2;
    const int* srcp = ei;
    const int* dstp = ei + e;

    size_t off = 0;
    auto alloc = [&](size_t bytes) -> char* {
        char* p = (char*)d_ws + off;
        off += (bytes + 255) & ~(size_t)255;
        return p;
    };
    int*   cnt      = (int*)alloc((size_t)n * 4);
    int*   cursor   = (int*)alloc((size_t)n * 4);
    int*   rowstart = (int*)alloc((size_t)(n + 1) * 4);
    int*   partial  = (int*)alloc(1024 * 4);
    int*   csr_src  = (int*)alloc((size_t)e * 4);
    float* csr_norm = (float*)alloc((size_t)e * 4);
    float* dinv     = (float*)alloc((size_t)n * 4);
    float* bufA     = (float*)alloc((size_t)n * F_HID * 4);  // agg_x(128) then agg(h1)(256)
    float* bufB     = (float*)alloc((size_t)n * F_HID * 4);  // h1 then h2
    float* hw3      = (float*)alloc((size_t)n * F_OUT * 4);

    const int TB = 256;
    hipMemsetAsync(cnt, 0, (size_t)n * 4, stream);
    hipMemsetAsync(cursor, 0, (size_t)n * 4, stream);

    count_kernel<<<(e + TB - 1) / TB, TB, 0, stream>>>(dstp, cnt, e);
    dinv_kernel<<<(n + TB - 1) / TB, TB, 0, stream>>>(cnt, dinv, n);
    int nb = (n + TB - 1) / TB;
    scan1_kernel<<<nb, TB, 0, stream>>>(cnt, rowstart, partial, n);
    scan2_kernel<<<1, TB, 0, stream>>>(partial, nb);
    scan3_kernel<<<nb, TB, 0, stream>>>(rowstart, partial, n, e);
    fill_kernel<<<(e + TB - 1) / TB, TB, 0, stream>>>(srcp, dstp, rowstart, cursor, dinv,
                                                      csr_src, csr_norm, e);

    // Layer 1: aggregate x (128-dim), then GEMM+bias+relu -> h1 (bufB)
    agg_kernel<F_IN><<<n, F_IN, 0, stream>>>(x, rowstart, csr_src, csr_norm, dinv, bufA, n);
    dim3 g1((n + 63) / 64, F_HID / 64);
    gemm_kernel<F_IN, true><<<g1, 256, 0, stream>>>(bufA, W1, b1, bufB, n, F_HID);

    // Layer 2: aggregate h1 (256-dim) -> bufA, GEMM+bias+relu -> h2 (bufB)
    agg_kernel<F_HID><<<n, F_HID, 0, stream>>>(bufB, rowstart, csr_src, csr_norm, dinv, bufA, n);
    gemm_kernel<F_HID, true><<<g1, 256, 0, stream>>>(bufA, W2, b2, bufB, n, F_HID);

    // Layer 3: GEMM to 10-dim, aggregate 10-dim + bias + log_softmax
    gemm3_kernel<<<(n + TB - 1) / TB, TB, 0, stream>>>(bufB, W3, hw3, n);
    final_kernel<<<(n + TB - 1) / TB, TB, 0, stream>>>(hw3, rowstart, csr_src, csr_norm, dinv,
                                                       b3, out, n);
}

// Round 2
// 455.652 us; speedup vs baseline: 1.1556x; 1.1556x over previous
//
#include <hip/hip_runtime.h>
#include <math.h>

#define F_IN 128
#define F_HID 256
#define F_OUT 10

// ---------------- degree / CSR build ----------------

__global__ void count_kernel(const int* __restrict__ dst, int* __restrict__ cnt, int e) {
    int i = blockIdx.x * blockDim.x + threadIdx.x;
    if (i < e) atomicAdd(&cnt[dst[i]], 1);
}

__global__ void dinv_kernel(const int* __restrict__ cnt, float* __restrict__ dinv, int n) {
    int i = blockIdx.x * blockDim.x + threadIdx.x;
    if (i < n) dinv[i] = rsqrtf((float)(cnt[i] + 1));  // +1 self loop
}

__global__ void scan1_kernel(const int* __restrict__ cnt, int* __restrict__ rowstart,
                             int* __restrict__ partial, int n) {
    __shared__ int s[256];
    int tid = threadIdx.x;
    int i = blockIdx.x * 256 + tid;
    int v = (i < n) ? cnt[i] : 0;
    s[tid] = v;
    __syncthreads();
    for (int off = 1; off < 256; off <<= 1) {
        int t = (tid >= off) ? s[tid - off] : 0;
        __syncthreads();
        s[tid] += t;
        __syncthreads();
    }
    if (i < n) rowstart[i] = s[tid] - v;          // exclusive
    if (tid == 255) partial[blockIdx.x] = s[255]; // block total
}

__global__ void scan2_kernel(int* __restrict__ partial, int nb) {
    __shared__ int s[256];
    int tid = threadIdx.x;
    int v = (tid < nb) ? partial[tid] : 0;
    s[tid] = v;
    __syncthreads();
    for (int off = 1; off < 256; off <<= 1) {
        int t = (tid >= off) ? s[tid - off] : 0;
        __syncthreads();
        s[tid] += t;
        __syncthreads();
    }
    if (tid < nb) partial[tid] = s[tid] - v;      // exclusive block offsets
}

__global__ void scan3_kernel(int* __restrict__ rowstart, const int* __restrict__ partial,
                             int n, int e) {
    int i = blockIdx.x * blockDim.x + threadIdx.x;
    if (i < n) rowstart[i] += partial[blockIdx.x];
    if (i == 0) rowstart[n] = e;
}

__global__ void fill_kernel(const int* __restrict__ src, const int* __restrict__ dst,
                            const int* __restrict__ rowstart, int* __restrict__ cursor,
                            const float* __restrict__ dinv, int* __restrict__ csr_src,
                            float* __restrict__ csr_norm, int e) {
    int i = blockIdx.x * blockDim.x + threadIdx.x;
    if (i >= e) return;
    int s = src[i], d = dst[i];
    int pos = rowstart[d] + atomicAdd(&cursor[d], 1);
    csr_src[pos] = s;
    csr_norm[pos] = dinv[s] * dinv[d];
}

// ---------------- feature aggregation: wave per node, VEC floats per lane ----------------
// F=256 -> float4/lane; F=128 -> float2/lane. Edge loop unrolled x4 for MLP.

template <int F>
__global__ __launch_bounds__(256) void agg_kernel(const float* __restrict__ feat,
                                                  const int* __restrict__ rowstart,
                                                  const int* __restrict__ csr_src,
                                                  const float* __restrict__ csr_norm,
                                                  const float* __restrict__ dinv,
                                                  float* __restrict__ out, int n) {
    constexpr int VEC = F / 64;
    int wid = threadIdx.x >> 6;
    int lane = threadIdx.x & 63;
    int v = blockIdx.x * 4 + wid;
    if (v >= n) return;

    float d = dinv[v];
    float sw = d * d;
    float acc[VEC];
    {
        const float* p = feat + (size_t)v * F + lane * VEC;
        if constexpr (VEC == 4) {
            float4 t = *(const float4*)p;
            acc[0] = sw * t.x; acc[1] = sw * t.y; acc[2] = sw * t.z; acc[3] = sw * t.w;
        } else {
            float2 t = *(const float2*)p;
            acc[0] = sw * t.x; acc[1] = sw * t.y;
        }
    }

    int e0 = rowstart[v], e1 = rowstart[v + 1];
    int e = e0;
    for (; e + 4 <= e1; e += 4) {
        int s[4];
        float w[4];
#pragma unroll
        for (int u = 0; u < 4; ++u) {
            s[u] = csr_src[e + u];
            w[u] = csr_norm[e + u];
        }
        float fv[4][VEC];
#pragma unroll
        for (int u = 0; u < 4; ++u) {
            const float* p = feat + (size_t)s[u] * F + lane * VEC;
            if constexpr (VEC == 4) {
                float4 t = *(const float4*)p;
                fv[u][0] = t.x; fv[u][1] = t.y; fv[u][2] = t.z; fv[u][3] = t.w;
            } else {
                float2 t = *(const float2*)p;
                fv[u][0] = t.x; fv[u][1] = t.y;
            }
        }
#pragma unroll
        for (int u = 0; u < 4; ++u)
#pragma unroll
            for (int j = 0; j < VEC; ++j) acc[j] += w[u] * fv[u][j];
    }
    for (; e < e1; ++e) {
        int s = csr_src[e];
        float w = csr_norm[e];
        const float* p = feat + (size_t)s * F + lane * VEC;
        if constexpr (VEC == 4) {
            float4 t = *(const float4*)p;
            acc[0] += w * t.x; acc[1] += w * t.y; acc[2] += w * t.z; acc[3] += w * t.w;
        } else {
            float2 t = *(const float2*)p;
            acc[0] += w * t.x; acc[1] += w * t.y;
        }
    }

    float* po = out + (size_t)v * F + lane * VEC;
    if constexpr (VEC == 4) {
        *(float4*)po = make_float4(acc[0], acc[1], acc[2], acc[3]);
    } else {
        *(float2*)po = make_float2(acc[0], acc[1]);
    }
}

// ---------------- fp32 tiled GEMM: C[M,N] = A[M,K] @ B[K,N] (+bias, relu) ----------------
// 64x64 tile per 256-thread block, 4x4 per thread, BK=16.

template <int K, bool RELU>
__global__ __launch_bounds__(256) void gemm_kernel(const float* __restrict__ A,
                                                   const float* __restrict__ B,
                                                   const float* __restrict__ bias,
                                                   float* __restrict__ C, int M, int N) {
    __shared__ float As[16][68];  // transposed: As[k][row], padded
    __shared__ float Bs[16][64];
    int tid = threadIdx.x;
    int tx = tid & 15, ty = tid >> 4;
    int arow = tid >> 2;
    int acol = (tid & 3) * 4;
    int brow = tid >> 4;
    int bcol = (tid & 15) * 4;
    int bm = blockIdx.x, bn = blockIdx.y;
    int grow = bm * 64 + arow;

    float acc[4][4] = {};

    for (int k0 = 0; k0 < K; k0 += 16) {
        float4 a4 = make_float4(0.f, 0.f, 0.f, 0.f);
        if (grow < M) a4 = *(const float4*)&A[(size_t)grow * K + k0 + acol];
        As[acol + 0][arow] = a4.x;
        As[acol + 1][arow] = a4.y;
        As[acol + 2][arow] = a4.z;
        As[acol + 3][arow] = a4.w;
        float4 b4 = *(const float4*)&B[(size_t)(k0 + brow) * N + bn * 64 + bcol];
        *(float4*)&Bs[brow][bcol] = b4;
        __syncthreads();
#pragma unroll
        for (int k = 0; k < 16; ++k) {
            float4 av = *(const float4*)&As[k][ty * 4];
            float4 bv = *(const float4*)&Bs[k][tx * 4];
            float a[4] = {av.x, av.y, av.z, av.w};
            float b[4] = {bv.x, bv.y, bv.z, bv.w};
#pragma unroll
            for (int i = 0; i < 4; ++i)
#pragma unroll
                for (int j = 0; j < 4; ++j) acc[i][j] += a[i] * b[j];
        }
        __syncthreads();
    }

    int row0 = bm * 64 + ty * 4;
    int col0 = bn * 64 + tx * 4;
#pragma unroll
    for (int i = 0; i < 4; ++i) {
        if (row0 + i >= M) break;
#pragma unroll
        for (int j = 0; j < 4; ++j) {
            float v = acc[i][j] + bias[col0 + j];
            if (RELU) v = fmaxf(v, 0.f);
            C[(size_t)(row0 + i) * N + col0 + j] = v;
        }
    }
}

// ---------------- small GEMM: hw3[M,10] = h[M,256] @ W3[256,10] ----------------

__global__ void gemm3_kernel(const float* __restrict__ h, const float* __restrict__ W3,
                             float* __restrict__ hw3, int M) {
    __shared__ float w[F_HID * F_OUT];
    for (int i = threadIdx.x; i < F_HID * F_OUT; i += blockDim.x) w[i] = W3[i];
    __syncthreads();
    int r = blockIdx.x * blockDim.x + threadIdx.x;
    if (r >= M) return;
    float acc[F_OUT] = {};
    const float* row = &h[(size_t)r * F_HID];
    for (int k = 0; k < F_HID; k += 4) {
        float4 hv = *(const float4*)&row[k];
#pragma unroll
        for (int j = 0; j < F_OUT; ++j) {
            acc[j] += hv.x * w[(k + 0) * F_OUT + j];
            acc[j] += hv.y * w[(k + 1) * F_OUT + j];
            acc[j] += hv.z * w[(k + 2) * F_OUT + j];
            acc[j] += hv.w * w[(k + 3) * F_OUT + j];
        }
    }
#pragma unroll
    for (int j = 0; j < F_OUT; ++j) hw3[(size_t)r * F_OUT + j] = acc[j];
}

// ---------------- final: 10-dim aggregation + bias + log_softmax ----------------

__global__ void final_kernel(const float* __restrict__ hw3, const int* __restrict__ rowstart,
                             const int* __restrict__ csr_src, const float* __restrict__ csr_norm,
                             const float* __restrict__ dinv, const float* __restrict__ b3,
                             float* __restrict__ out, int n) {
    int v = blockIdx.x * blockDim.x + threadIdx.x;
    if (v >= n) return;
    float acc[F_OUT];
    float d = dinv[v];
    float sw = d * d;
#pragma unroll
    for (int j = 0; j < F_OUT; ++j) acc[j] = sw * hw3[(size_t)v * F_OUT + j];
    int e0 = rowstart[v], e1 = rowstart[v + 1];
    for (int e = e0; e < e1; ++e) {
        int s = csr_src[e];
        float w = csr_norm[e];
#pragma unroll
        for (int j = 0; j < F_OUT; ++j) acc[j] += w * hw3[(size_t)s * F_OUT + j];
    }
#pragma unroll
    for (int j = 0; j < F_OUT; ++j) acc[j] += b3[j];
    float m = acc[0];
#pragma unroll
    for (int j = 1; j < F_OUT; ++j) m = fmaxf(m, acc[j]);
    float sum = 0.f;
#pragma unroll
    for (int j = 0; j < F_OUT; ++j) sum += expf(acc[j] - m);
    float lse = m + logf(sum);
#pragma unroll
    for (int j = 0; j < F_OUT; ++j) out[(size_t)v * F_OUT + j] = acc[j] - lse;
}

// ---------------- launch ----------------

extern "C" void kernel_launch(void* const* d_in, const int* in_sizes, int n_in,
                              void* d_out, int out_size, void* d_ws, size_t ws_size,
                              hipStream_t stream) {
    const float* x  = (const float*)d_in[0];
    const int*   ei = (const int*)d_in[1];
    const float* W1 = (const float*)d_in[2];
    const float* b1 = (const float*)d_in[3];
    const float* W2 = (const float*)d_in[4];
    const float* b2 = (const float*)d_in[5];
    const float* W3 = (const float*)d_in[6];
    const float* b3 = (const float*)d_in[7];
    float* out = (float*)d_out;

    int n = in_sizes[0] / F_IN;
    int e = in_sizes[1] / 2;
    const int* srcp = ei;
    const int* dstp = ei + e;

    size_t off = 0;
    auto alloc = [&](size_t bytes) -> char* {
        char* p = (char*)d_ws + off;
        off += (bytes + 255) & ~(size_t)255;
        return p;
    };
    int*   cnt      = (int*)alloc((size_t)n * 4);
    int*   cursor   = (int*)alloc((size_t)n * 4);
    int*   rowstart = (int*)alloc((size_t)(n + 1) * 4);
    int*   partial  = (int*)alloc(1024 * 4);
    int*   csr_src  = (int*)alloc((size_t)e * 4);
    float* csr_norm = (float*)alloc((size_t)e * 4);
    float* dinv     = (float*)alloc((size_t)n * 4);
    float* bufA     = (float*)alloc((size_t)n * F_HID * 4);  // agg_x(128) then agg(h1)(256)
    float* bufB     = (float*)alloc((size_t)n * F_HID * 4);  // h1 then h2
    float* hw3      = (float*)alloc((size_t)n * F_OUT * 4);

    const int TB = 256;
    hipMemsetAsync(cnt, 0, (size_t)n * 4, stream);
    hipMemsetAsync(cursor, 0, (size_t)n * 4, stream);

    count_kernel<<<(e + TB - 1) / TB, TB, 0, stream>>>(dstp, cnt, e);
    dinv_kernel<<<(n + TB - 1) / TB, TB, 0, stream>>>(cnt, dinv, n);
    int nb = (n + TB - 1) / TB;
    scan1_kernel<<<nb, TB, 0, stream>>>(cnt, rowstart, partial, n);
    scan2_kernel<<<1, TB, 0, stream>>>(partial, nb);
    scan3_kernel<<<nb, TB, 0, stream>>>(rowstart, partial, n, e);
    fill_kernel<<<(e + TB - 1) / TB, TB, 0, stream>>>(srcp, dstp, rowstart, cursor, dinv,
                                                      csr_src, csr_norm, e);

    int nwave = (n + 3) / 4;  // 4 waves (nodes) per 256-thread block

    // Layer 1: aggregate x (128-dim), then GEMM+bias+relu -> h1 (bufB)
    agg_kernel<F_IN><<<nwave, 256, 0, stream>>>(x, rowstart, csr_src, csr_norm, dinv, bufA, n);
    dim3 g1((n + 63) / 64, F_HID / 64);
    gemm_kernel<F_IN, true><<<g1, 256, 0, stream>>>(bufA, W1, b1, bufB, n, F_HID);

    // Layer 2: aggregate h1 (256-dim) -> bufA, GEMM+bias+relu -> h2 (bufB)
    agg_kernel<F_HID><<<nwave, 256, 0, stream>>>(bufB, rowstart, csr_src, csr_norm, dinv, bufA, n);
    gemm_kernel<F_HID, true><<<g1, 256, 0, stream>>>(bufA, W2, b2, bufB, n, F_HID);

    // Layer 3: GEMM to 10-dim, aggregate 10-dim + bias + log_softmax
    gemm3_kernel<<<(n + TB - 1) / TB, TB, 0, stream>>>(bufB, W3, hw3, n);
    final_kernel<<<(n + TB - 1) / TB, TB, 0, stream>>>(hw3, rowstart, csr_src, csr_norm, dinv,
                                                       b3, out, n);
}

// Round 3
// 379.098 us; speedup vs baseline: 1.3889x; 1.2019x over previous
//
#include <hip/hip_runtime.h>
#include <hip/hip_bf16.h>
#include <math.h>

#define F_IN 128
#define F_HID 256
#define F_OUT 10

static __device__ __forceinline__ float b2f(unsigned short u) {
    union { float f; unsigned int u; } c;
    c.u = ((unsigned int)u) << 16;
    return c.f;
}

// ---------------- degree / CSR build ----------------

__global__ void count_kernel(const int* __restrict__ dst, int* __restrict__ cnt, int e) {
    int i = blockIdx.x * blockDim.x + threadIdx.x;
    if (i < e) atomicAdd(&cnt[dst[i]], 1);
}

__global__ void dinv_kernel(const int* __restrict__ cnt, float* __restrict__ dinv, int n) {
    int i = blockIdx.x * blockDim.x + threadIdx.x;
    if (i < n) dinv[i] = rsqrtf((float)(cnt[i] + 1));  // +1 self loop
}

__global__ void scan1_kernel(const int* __restrict__ cnt, int* __restrict__ rowstart,
                             int* __restrict__ partial, int n) {
    __shared__ int s[256];
    int tid = threadIdx.x;
    int i = blockIdx.x * 256 + tid;
    int v = (i < n) ? cnt[i] : 0;
    s[tid] = v;
    __syncthreads();
    for (int off = 1; off < 256; off <<= 1) {
        int t = (tid >= off) ? s[tid - off] : 0;
        __syncthreads();
        s[tid] += t;
        __syncthreads();
    }
    if (i < n) rowstart[i] = s[tid] - v;          // exclusive
    if (tid == 255) partial[blockIdx.x] = s[255]; // block total
}

__global__ void scan2_kernel(int* __restrict__ partial, int nb) {
    __shared__ int s[256];
    int tid = threadIdx.x;
    int v = (tid < nb) ? partial[tid] : 0;
    s[tid] = v;
    __syncthreads();
    for (int off = 1; off < 256; off <<= 1) {
        int t = (tid >= off) ? s[tid - off] : 0;
        __syncthreads();
        s[tid] += t;
        __syncthreads();
    }
    if (tid < nb) partial[tid] = s[tid] - v;      // exclusive block offsets
}

__global__ void scan3_kernel(int* __restrict__ rowstart, const int* __restrict__ partial,
                             int n, int e) {
    int i = blockIdx.x * blockDim.x + threadIdx.x;
    if (i < n) rowstart[i] += partial[blockIdx.x];
    if (i == 0) rowstart[n] = e;
}

__global__ void fill_kernel(const int* __restrict__ src, const int* __restrict__ dst,
                            const int* __restrict__ rowstart, int* __restrict__ cursor,
                            const float* __restrict__ dinv, int* __restrict__ csr_src,
                            float* __restrict__ csr_norm, int e) {
    int i = blockIdx.x * blockDim.x + threadIdx.x;
    if (i >= e) return;
    int s = src[i], d = dst[i];
    int pos = rowstart[d] + atomicAdd(&cursor[d], 1);
    csr_src[pos] = s;
    csr_norm[pos] = dinv[s] * dinv[d];
}

// ---------------- fp32 -> bf16 cast (RNE) ----------------

__global__ void cast_kernel(const float* __restrict__ in, unsigned short* __restrict__ out,
                            size_t total) {
    size_t i = (size_t)(blockIdx.x * blockDim.x + threadIdx.x) * 4;
    if (i >= total) return;
    float4 v = *(const float4*)&in[i];
    ushort4 o;
    o.x = __bfloat16_as_ushort(__float2bfloat16(v.x));
    o.y = __bfloat16_as_ushort(__float2bfloat16(v.y));
    o.z = __bfloat16_as_ushort(__float2bfloat16(v.z));
    o.w = __bfloat16_as_ushort(__float2bfloat16(v.w));
    *(ushort4*)&out[i] = o;
}

// ---------------- bf16 feature aggregation: wave per node ----------------
// F=256 -> 4 bf16/lane; F=128 -> 2 bf16/lane. Edge loop unrolled x8.

template <int F>
__global__ __launch_bounds__(256) void agg_bf16_kernel(const unsigned short* __restrict__ feat,
                                                       const int* __restrict__ rowstart,
                                                       const int* __restrict__ csr_src,
                                                       const float* __restrict__ csr_norm,
                                                       const float* __restrict__ dinv,
                                                       float* __restrict__ out, int n) {
    constexpr int VEC = F / 64;
    int wid = threadIdx.x >> 6;
    int lane = threadIdx.x & 63;
    int v = blockIdx.x * 4 + wid;
    if (v >= n) return;

    float d = dinv[v];
    float sw = d * d;
    float acc[VEC];

    auto loadrow = [&](int node, float (&dst)[VEC]) {
        const unsigned short* p = feat + (size_t)node * F + lane * VEC;
        if constexpr (VEC == 4) {
            ushort4 t = *(const ushort4*)p;
            dst[0] = b2f(t.x); dst[1] = b2f(t.y); dst[2] = b2f(t.z); dst[3] = b2f(t.w);
        } else {
            ushort2 t = *(const ushort2*)p;
            dst[0] = b2f(t.x); dst[1] = b2f(t.y);
        }
    };

    {
        float t[VEC];
        loadrow(v, t);
#pragma unroll
        for (int j = 0; j < VEC; ++j) acc[j] = sw * t[j];
    }

    int e0 = rowstart[v], e1 = rowstart[v + 1];
    int e = e0;
    for (; e + 8 <= e1; e += 8) {
        int s[8];
        float w[8];
#pragma unroll
        for (int u = 0; u < 8; ++u) {
            s[u] = csr_src[e + u];
            w[u] = csr_norm[e + u];
        }
        float fv[8][VEC];
#pragma unroll
        for (int u = 0; u < 8; ++u) loadrow(s[u], fv[u]);
#pragma unroll
        for (int u = 0; u < 8; ++u)
#pragma unroll
            for (int j = 0; j < VEC; ++j) acc[j] += w[u] * fv[u][j];
    }
    for (; e + 4 <= e1; e += 4) {
        int s[4];
        float w[4];
#pragma unroll
        for (int u = 0; u < 4; ++u) {
            s[u] = csr_src[e + u];
            w[u] = csr_norm[e + u];
        }
        float fv[4][VEC];
#pragma unroll
        for (int u = 0; u < 4; ++u) loadrow(s[u], fv[u]);
#pragma unroll
        for (int u = 0; u < 4; ++u)
#pragma unroll
            for (int j = 0; j < VEC; ++j) acc[j] += w[u] * fv[u][j];
    }
    for (; e < e1; ++e) {
        int s = csr_src[e];
        float w = csr_norm[e];
        float fv[VEC];
        loadrow(s, fv);
#pragma unroll
        for (int j = 0; j < VEC; ++j) acc[j] += w * fv[j];
    }

    float* po = out + (size_t)v * F + lane * VEC;
    if constexpr (VEC == 4) {
        *(float4*)po = make_float4(acc[0], acc[1], acc[2], acc[3]);
    } else {
        *(float2*)po = make_float2(acc[0], acc[1]);
    }
}

// ---------------- fp32 tiled GEMM: C[M,N] = A[M,K] @ B[K,N] (+bias, relu) ----------------
// 64x64 tile per 256-thread block, 4x4 per thread, BK=16. Optional bf16 output.

template <int K, bool RELU, bool BF16OUT>
__global__ __launch_bounds__(256) void gemm_kernel(const float* __restrict__ A,
                                                   const float* __restrict__ B,
                                                   const float* __restrict__ bias,
                                                   float* __restrict__ C,
                                                   unsigned short* __restrict__ Cb,
                                                   int M, int N) {
    __shared__ float As[16][68];  // transposed: As[k][row], padded
    __shared__ float Bs[16][64];
    int tid = threadIdx.x;
    int tx = tid & 15, ty = tid >> 4;
    int arow = tid >> 2;
    int acol = (tid & 3) * 4;
    int brow = tid >> 4;
    int bcol = (tid & 15) * 4;
    int bm = blockIdx.x, bn = blockIdx.y;
    int grow = bm * 64 + arow;

    float acc[4][4] = {};

    for (int k0 = 0; k0 < K; k0 += 16) {
        float4 a4 = make_float4(0.f, 0.f, 0.f, 0.f);
        if (grow < M) a4 = *(const float4*)&A[(size_t)grow * K + k0 + acol];
        As[acol + 0][arow] = a4.x;
        As[acol + 1][arow] = a4.y;
        As[acol + 2][arow] = a4.z;
        As[acol + 3][arow] = a4.w;
        float4 b4 = *(const float4*)&B[(size_t)(k0 + brow) * N + bn * 64 + bcol];
        *(float4*)&Bs[brow][bcol] = b4;
        __syncthreads();
#pragma unroll
        for (int k = 0; k < 16; ++k) {
            float4 av = *(const float4*)&As[k][ty * 4];
            float4 bv = *(const float4*)&Bs[k][tx * 4];
            float a[4] = {av.x, av.y, av.z, av.w};
            float b[4] = {bv.x, bv.y, bv.z, bv.w};
#pragma unroll
            for (int i = 0; i < 4; ++i)
#pragma unroll
                for (int j = 0; j < 4; ++j) acc[i][j] += a[i] * b[j];
        }
        __syncthreads();
    }

    int row0 = bm * 64 + ty * 4;
    int col0 = bn * 64 + tx * 4;
#pragma unroll
    for (int i = 0; i < 4; ++i) {
        if (row0 + i >= M) break;
        float v[4];
#pragma unroll
        for (int j = 0; j < 4; ++j) {
            v[j] = acc[i][j] + bias[col0 + j];
            if (RELU) v[j] = fmaxf(v[j], 0.f);
        }
        if constexpr (BF16OUT) {
            ushort4 o;
            o.x = __bfloat16_as_ushort(__float2bfloat16(v[0]));
            o.y = __bfloat16_as_ushort(__float2bfloat16(v[1]));
            o.z = __bfloat16_as_ushort(__float2bfloat16(v[2]));
            o.w = __bfloat16_as_ushort(__float2bfloat16(v[3]));
            *(ushort4*)&Cb[(size_t)(row0 + i) * N + col0] = o;
        } else {
            *(float4*)&C[(size_t)(row0 + i) * N + col0] =
                make_float4(v[0], v[1], v[2], v[3]);
        }
    }
}

// ---------------- small GEMM: hw3[M,10] = h[M,256] @ W3[256,10] ----------------

__global__ void gemm3_kernel(const float* __restrict__ h, const float* __restrict__ W3,
                             float* __restrict__ hw3, int M) {
    __shared__ float w[F_HID * F_OUT];
    for (int i = threadIdx.x; i < F_HID * F_OUT; i += blockDim.x) w[i] = W3[i];
    __syncthreads();
    int r = blockIdx.x * blockDim.x + threadIdx.x;
    if (r >= M) return;
    float acc[F_OUT] = {};
    const float* row = &h[(size_t)r * F_HID];
    for (int k = 0; k < F_HID; k += 4) {
        float4 hv = *(const float4*)&row[k];
#pragma unroll
        for (int j = 0; j < F_OUT; ++j) {
            acc[j] += hv.x * w[(k + 0) * F_OUT + j];
            acc[j] += hv.y * w[(k + 1) * F_OUT + j];
            acc[j] += hv.z * w[(k + 2) * F_OUT + j];
            acc[j] += hv.w * w[(k + 3) * F_OUT + j];
        }
    }
#pragma unroll
    for (int j = 0; j < F_OUT; ++j) hw3[(size_t)r * F_OUT + j] = acc[j];
}

// ---------------- final: 10-dim aggregation + bias + log_softmax ----------------

__global__ void final_kernel(const float* __restrict__ hw3, const int* __restrict__ rowstart,
                             const int* __restrict__ csr_src, const float* __restrict__ csr_norm,
                             const float* __restrict__ dinv, const float* __restrict__ b3,
                             float* __restrict__ out, int n) {
    int v = blockIdx.x * blockDim.x + threadIdx.x;
    if (v >= n) return;
    float acc[F_OUT];
    float d = dinv[v];
    float sw = d * d;
#pragma unroll
    for (int j = 0; j < F_OUT; ++j) acc[j] = sw * hw3[(size_t)v * F_OUT + j];
    int e0 = rowstart[v], e1 = rowstart[v + 1];
    for (int e = e0; e < e1; ++e) {
        int s = csr_src[e];
        float w = csr_norm[e];
#pragma unroll
        for (int j = 0; j < F_OUT; ++j) acc[j] += w * hw3[(size_t)s * F_OUT + j];
    }
#pragma unroll
    for (int j = 0; j < F_OUT; ++j) acc[j] += b3[j];
    float m = acc[0];
#pragma unroll
    for (int j = 1; j < F_OUT; ++j) m = fmaxf(m, acc[j]);
    float sum = 0.f;
#pragma unroll
    for (int j = 0; j < F_OUT; ++j) sum += expf(acc[j] - m);
    float lse = m + logf(sum);
#pragma unroll
    for (int j = 0; j < F_OUT; ++j) out[(size_t)v * F_OUT + j] = acc[j] - lse;
}

// ---------------- launch ----------------

extern "C" void kernel_launch(void* const* d_in, const int* in_sizes, int n_in,
                              void* d_out, int out_size, void* d_ws, size_t ws_size,
                              hipStream_t stream) {
    const float* x  = (const float*)d_in[0];
    const int*   ei = (const int*)d_in[1];
    const float* W1 = (const float*)d_in[2];
    const float* b1 = (const float*)d_in[3];
    const float* W2 = (const float*)d_in[4];
    const float* b2 = (const float*)d_in[5];
    const float* W3 = (const float*)d_in[6];
    const float* b3 = (const float*)d_in[7];
    float* out = (float*)d_out;

    int n = in_sizes[0] / F_IN;
    int e = in_sizes[1] / 2;
    const int* srcp = ei;
    const int* dstp = ei + e;

    size_t off = 0;
    auto alloc = [&](size_t bytes) -> char* {
        char* p = (char*)d_ws + off;
        off += (bytes + 255) & ~(size_t)255;
        return p;
    };
    int*   cnt      = (int*)alloc((size_t)n * 4);
    int*   cursor   = (int*)alloc((size_t)n * 4);
    int*   rowstart = (int*)alloc((size_t)(n + 1) * 4);
    int*   partial  = (int*)alloc(1024 * 4);
    int*   csr_src  = (int*)alloc((size_t)e * 4);
    float* csr_norm = (float*)alloc((size_t)e * 4);
    float* dinv     = (float*)alloc((size_t)n * 4);
    unsigned short* xb  = (unsigned short*)alloc((size_t)n * F_IN * 2);   // x in bf16
    unsigned short* h1b = (unsigned short*)alloc((size_t)n * F_HID * 2);  // h1 in bf16
    float* bufA     = (float*)alloc((size_t)n * F_HID * 4);  // agg outputs (fp32)
    float* bufB     = (float*)alloc((size_t)n * F_HID * 4);  // h2 (fp32)
    float* hw3      = (float*)alloc((size_t)n * F_OUT * 4);

    const int TB = 256;
    hipMemsetAsync(cnt, 0, (size_t)n * 4, stream);
    hipMemsetAsync(cursor, 0, (size_t)n * 4, stream);

    count_kernel<<<(e + TB - 1) / TB, TB, 0, stream>>>(dstp, cnt, e);
    dinv_kernel<<<(n + TB - 1) / TB, TB, 0, stream>>>(cnt, dinv, n);
    int nb = (n + TB - 1) / TB;
    scan1_kernel<<<nb, TB, 0, stream>>>(cnt, rowstart, partial, n);
    scan2_kernel<<<1, TB, 0, stream>>>(partial, nb);
    scan3_kernel<<<nb, TB, 0, stream>>>(rowstart, partial, n, e);
    fill_kernel<<<(e + TB - 1) / TB, TB, 0, stream>>>(srcp, dstp, rowstart, cursor, dinv,
                                                      csr_src, csr_norm, e);

    // Cast x -> bf16 table for layer-1 gather
    size_t xtotal = (size_t)n * F_IN;
    cast_kernel<<<(int)((xtotal / 4 + TB - 1) / TB), TB, 0, stream>>>(x, xb, xtotal);

    int nwave = (n + 3) / 4;  // 4 waves (nodes) per 256-thread block
    dim3 g1((n + 63) / 64, F_HID / 64);

    // Layer 1: aggregate x_bf16 (128-dim) -> bufA, GEMM+bias+relu -> h1 (bf16)
    agg_bf16_kernel<F_IN><<<nwave, 256, 0, stream>>>(xb, rowstart, csr_src, csr_norm, dinv,
                                                     bufA, n);
    gemm_kernel<F_IN, true, true><<<g1, 256, 0, stream>>>(bufA, W1, b1, nullptr, h1b, n, F_HID);

    // Layer 2: aggregate h1_bf16 (256-dim) -> bufA, GEMM+bias+relu -> h2 (fp32)
    agg_bf16_kernel<F_HID><<<nwave, 256, 0, stream>>>(h1b, rowstart, csr_src, csr_norm, dinv,
                                                      bufA, n);
    gemm_kernel<F_HID, true, false><<<g1, 256, 0, stream>>>(bufA, W2, b2, bufB, nullptr, n, F_HID);

    // Layer 3: GEMM to 10-dim, aggregate 10-dim + bias + log_softmax
    gemm3_kernel<<<(n + TB - 1) / TB, TB, 0, stream>>>(bufB, W3, hw3, n);
    final_kernel<<<(n + TB - 1) / TB, TB, 0, stream>>>(hw3, rowstart, csr_src, csr_norm, dinv,
                                                       b3, out, n);
}

// Round 4
// 282.578 us; speedup vs baseline: 1.8633x; 1.3416x over previous
//
#include <hip/hip_runtime.h>
#include <hip/hip_bf16.h>
#include <math.h>

#define F_IN 128
#define F_HID 256
#define F_OUT 10

typedef __attribute__((ext_vector_type(4))) short s16x4;
typedef __attribute__((ext_vector_type(8))) short s16x8;
typedef __attribute__((ext_vector_type(4))) float f32x4;

static __device__ __forceinline__ float b2f(unsigned short u) {
    union { float f; unsigned int u; } c;
    c.u = ((unsigned int)u) << 16;
    return c.f;
}
static __device__ __forceinline__ unsigned short f2b(float f) {
    return __bfloat16_as_ushort(__float2bfloat16(f));
}

// ---------------- degree / CSR build ----------------

__global__ void count_kernel(const int* __restrict__ dst, int* __restrict__ cnt, int e) {
    int i = blockIdx.x * blockDim.x + threadIdx.x;
    if (i < e) atomicAdd(&cnt[dst[i]], 1);
}

__global__ void dinv_kernel(const int* __restrict__ cnt, float* __restrict__ dinv, int n) {
    int i = blockIdx.x * blockDim.x + threadIdx.x;
    if (i < n) dinv[i] = rsqrtf((float)(cnt[i] + 1));  // +1 self loop
}

__global__ void scan1_kernel(const int* __restrict__ cnt, int* __restrict__ rowstart,
                             int* __restrict__ partial, int n) {
    __shared__ int s[256];
    int tid = threadIdx.x;
    int i = blockIdx.x * 256 + tid;
    int v = (i < n) ? cnt[i] : 0;
    s[tid] = v;
    __syncthreads();
    for (int off = 1; off < 256; off <<= 1) {
        int t = (tid >= off) ? s[tid - off] : 0;
        __syncthreads();
        s[tid] += t;
        __syncthreads();
    }
    if (i < n) rowstart[i] = s[tid] - v;          // exclusive
    if (tid == 255) partial[blockIdx.x] = s[255]; // block total
}

__global__ void scan2_kernel(int* __restrict__ partial, int nb) {
    __shared__ int s[256];
    int tid = threadIdx.x;
    int v = (tid < nb) ? partial[tid] : 0;
    s[tid] = v;
    __syncthreads();
    for (int off = 1; off < 256; off <<= 1) {
        int t = (tid >= off) ? s[tid - off] : 0;
        __syncthreads();
        s[tid] += t;
        __syncthreads();
    }
    if (tid < nb) partial[tid] = s[tid] - v;      // exclusive block offsets
}

__global__ void scan3_kernel(int* __restrict__ rowstart, const int* __restrict__ partial,
                             int n, int e) {
    int i = blockIdx.x * blockDim.x + threadIdx.x;
    if (i < n) rowstart[i] += partial[blockIdx.x];
    if (i == 0) rowstart[n] = e;
}

__global__ void fill_kernel(const int* __restrict__ src, const int* __restrict__ dst,
                            const int* __restrict__ rowstart, int* __restrict__ cursor,
                            const float* __restrict__ dinv, int* __restrict__ csr_src,
                            float* __restrict__ csr_norm, int e) {
    int i = blockIdx.x * blockDim.x + threadIdx.x;
    if (i >= e) return;
    int s = src[i], d = dst[i];
    int pos = rowstart[d] + atomicAdd(&cursor[d], 1);
    csr_src[pos] = s;
    csr_norm[pos] = dinv[s] * dinv[d];
}

// ---------------- casts ----------------

__global__ void cast_kernel(const float* __restrict__ in, unsigned short* __restrict__ out,
                            size_t total) {
    size_t i = (size_t)(blockIdx.x * blockDim.x + threadIdx.x) * 4;
    if (i >= total) return;
    float4 v = *(const float4*)&in[i];
    ushort4 o;
    o.x = f2b(v.x); o.y = f2b(v.y); o.z = f2b(v.z); o.w = f2b(v.w);
    *(ushort4*)&out[i] = o;
}

// W [K][N] fp32 -> Wt [N][K] bf16
__global__ void castT_kernel(const float* __restrict__ in, unsigned short* __restrict__ out,
                             int Kd, int Nd) {
    int i = blockIdx.x * blockDim.x + threadIdx.x;
    if (i >= Kd * Nd) return;
    int k = i / Nd, nn = i - k * Nd;
    out[nn * Kd + k] = f2b(in[i]);
}

// ---------------- bf16 feature aggregation: wave per node, bf16 out ----------------

template <int F>
__global__ __launch_bounds__(256) void agg_bf16_kernel(const unsigned short* __restrict__ feat,
                                                       const int* __restrict__ rowstart,
                                                       const int* __restrict__ csr_src,
                                                       const float* __restrict__ csr_norm,
                                                       const float* __restrict__ dinv,
                                                       unsigned short* __restrict__ out, int n) {
    constexpr int VEC = F / 64;
    int wid = threadIdx.x >> 6;
    int lane = threadIdx.x & 63;
    int v = blockIdx.x * 4 + wid;
    if (v >= n) return;

    float d = dinv[v];
    float sw = d * d;
    float acc[VEC];

    auto loadrow = [&](int node, float (&dst)[VEC]) {
        const unsigned short* p = feat + (size_t)node * F + lane * VEC;
        if constexpr (VEC == 4) {
            ushort4 t = *(const ushort4*)p;
            dst[0] = b2f(t.x); dst[1] = b2f(t.y); dst[2] = b2f(t.z); dst[3] = b2f(t.w);
        } else {
            ushort2 t = *(const ushort2*)p;
            dst[0] = b2f(t.x); dst[1] = b2f(t.y);
        }
    };

    {
        float t[VEC];
        loadrow(v, t);
#pragma unroll
        for (int j = 0; j < VEC; ++j) acc[j] = sw * t[j];
    }

    int e0 = rowstart[v], e1 = rowstart[v + 1];
    int e = e0;
    for (; e + 8 <= e1; e += 8) {
        int s[8];
        float w[8];
#pragma unroll
        for (int u = 0; u < 8; ++u) {
            s[u] = csr_src[e + u];
            w[u] = csr_norm[e + u];
        }
        float fv[8][VEC];
#pragma unroll
        for (int u = 0; u < 8; ++u) loadrow(s[u], fv[u]);
#pragma unroll
        for (int u = 0; u < 8; ++u)
#pragma unroll
            for (int j = 0; j < VEC; ++j) acc[j] += w[u] * fv[u][j];
    }
    for (; e + 4 <= e1; e += 4) {
        int s[4];
        float w[4];
#pragma unroll
        for (int u = 0; u < 4; ++u) {
            s[u] = csr_src[e + u];
            w[u] = csr_norm[e + u];
        }
        float fv[4][VEC];
#pragma unroll
        for (int u = 0; u < 4; ++u) loadrow(s[u], fv[u]);
#pragma unroll
        for (int u = 0; u < 4; ++u)
#pragma unroll
            for (int j = 0; j < VEC; ++j) acc[j] += w[u] * fv[u][j];
    }
    for (; e < e1; ++e) {
        int s = csr_src[e];
        float w = csr_norm[e];
        float fv[VEC];
        loadrow(s, fv);
#pragma unroll
        for (int j = 0; j < VEC; ++j) acc[j] += w * fv[j];
    }

    unsigned short* po = out + (size_t)v * F + lane * VEC;
    if constexpr (VEC == 4) {
        ushort4 o;
        o.x = f2b(acc[0]); o.y = f2b(acc[1]); o.z = f2b(acc[2]); o.w = f2b(acc[3]);
        *(ushort4*)po = o;
    } else {
        ushort2 o;
        o.x = f2b(acc[0]); o.y = f2b(acc[1]);
        *(ushort2*)po = o;
    }
}

// ---------------- MFMA bf16 GEMM: C[M,N] = A[M,K]bf16 @ Wt[N,K]bf16^T (+bias, relu) ------
// 64x64 tile per 256-thread block (4 waves); wave w: rows w*16..w*16+15 x all 64 cols.
// mfma_f32_16x16x32_bf16. Consistent per-lane k-ordering for A and B fragments.

template <int K, bool RELU, bool BF16OUT>
__global__ __launch_bounds__(256) void gemm_mfma_kernel(const unsigned short* __restrict__ A,
                                                        const unsigned short* __restrict__ Bt,
                                                        const float* __restrict__ bias,
                                                        float* __restrict__ C,
                                                        unsigned short* __restrict__ Cb,
                                                        int M, int N) {
    __shared__ unsigned short As[64][40];  // 80B row stride: 16B-aligned, 2-way-max banks
    __shared__ unsigned short Bs[64][40];  // Bs[col][k]
    int tid = threadIdx.x;
    int w = tid >> 6;
    int lane = tid & 63;
    int g = lane >> 4;     // k-group
    int r16 = lane & 15;
    int bm = blockIdx.x, bn = blockIdx.y;

    int srow = tid >> 2;        // staging row 0..63
    int scol = (tid & 3) * 8;   // staging col 0,8,16,24
    int garow = bm * 64 + srow;
    int gbrow = bn * 64 + srow;

    f32x4 acc[4] = {};

    for (int k0 = 0; k0 < K; k0 += 32) {
        uint4 av = make_uint4(0, 0, 0, 0);
        if (garow < M) av = *(const uint4*)&A[(size_t)garow * K + k0 + scol];
        uint4 bv = *(const uint4*)&Bt[(size_t)gbrow * K + k0 + scol];
        __syncthreads();  // protect previous iteration's LDS reads
        *(uint4*)&As[srow][scol] = av;
        *(uint4*)&Bs[srow][scol] = bv;
        __syncthreads();

        union U { s16x8 v; s16x4 h[2]; };
        U af;
        int arow = w * 16 + r16;
        af.h[0] = *(const s16x4*)&As[arow][g * 4];
        af.h[1] = *(const s16x4*)&As[arow][g * 4 + 16];
#pragma unroll
        for (int cg = 0; cg < 4; ++cg) {
            U bf;
            bf.h[0] = *(const s16x4*)&Bs[cg * 16 + r16][g * 4];
            bf.h[1] = *(const s16x4*)&Bs[cg * 16 + r16][g * 4 + 16];
            acc[cg] = __builtin_amdgcn_mfma_f32_16x16x32_bf16(af.v, bf.v, acc[cg], 0, 0, 0);
        }
    }

    // epilogue: C/D layout col=lane&15, row=(lane>>4)*4+reg
#pragma unroll
    for (int cg = 0; cg < 4; ++cg) {
        int col = bn * 64 + cg * 16 + r16;
        float bs = bias[col];
#pragma unroll
        for (int r = 0; r < 4; ++r) {
            int row = bm * 64 + w * 16 + g * 4 + r;
            if (row < M) {
                float v = acc[cg][r] + bs;
                if (RELU) v = fmaxf(v, 0.f);
                if (BF16OUT) {
                    Cb[(size_t)row * N + col] = f2b(v);
                } else {
                    C[(size_t)row * N + col] = v;
                }
            }
        }
    }
}

// ---------------- small GEMM: hw3[M,10] = h[M,256] @ W3[256,10] ----------------

__global__ void gemm3_kernel(const float* __restrict__ h, const float* __restrict__ W3,
                             float* __restrict__ hw3, int M) {
    __shared__ float w[F_HID * F_OUT];
    for (int i = threadIdx.x; i < F_HID * F_OUT; i += blockDim.x) w[i] = W3[i];
    __syncthreads();
    int r = blockIdx.x * blockDim.x + threadIdx.x;
    if (r >= M) return;
    float acc[F_OUT] = {};
    const float* row = &h[(size_t)r * F_HID];
    for (int k = 0; k < F_HID; k += 4) {
        float4 hv = *(const float4*)&row[k];
#pragma unroll
        for (int j = 0; j < F_OUT; ++j) {
            acc[j] += hv.x * w[(k + 0) * F_OUT + j];
            acc[j] += hv.y * w[(k + 1) * F_OUT + j];
            acc[j] += hv.z * w[(k + 2) * F_OUT + j];
            acc[j] += hv.w * w[(k + 3) * F_OUT + j];
        }
    }
#pragma unroll
    for (int j = 0; j < F_OUT; ++j) hw3[(size_t)r * F_OUT + j] = acc[j];
}

// ---------------- final: 10-dim aggregation + bias + log_softmax ----------------

__global__ void final_kernel(const float* __restrict__ hw3, const int* __restrict__ rowstart,
                             const int* __restrict__ csr_src, const float* __restrict__ csr_norm,
                             const float* __restrict__ dinv, const float* __restrict__ b3,
                             float* __restrict__ out, int n) {
    int v = blockIdx.x * blockDim.x + threadIdx.x;
    if (v >= n) return;
    float acc[F_OUT];
    float d = dinv[v];
    float sw = d * d;
#pragma unroll
    for (int j = 0; j < F_OUT; ++j) acc[j] = sw * hw3[(size_t)v * F_OUT + j];
    int e0 = rowstart[v], e1 = rowstart[v + 1];
    for (int e = e0; e < e1; ++e) {
        int s = csr_src[e];
        float w = csr_norm[e];
#pragma unroll
        for (int j = 0; j < F_OUT; ++j) acc[j] += w * hw3[(size_t)s * F_OUT + j];
    }
#pragma unroll
    for (int j = 0; j < F_OUT; ++j) acc[j] += b3[j];
    float m = acc[0];
#pragma unroll
    for (int j = 1; j < F_OUT; ++j) m = fmaxf(m, acc[j]);
    float sum = 0.f;
#pragma unroll
    for (int j = 0; j < F_OUT; ++j) sum += expf(acc[j] - m);
    float lse = m + logf(sum);
#pragma unroll
    for (int j = 0; j < F_OUT; ++j) out[(size_t)v * F_OUT + j] = acc[j] - lse;
}

// ---------------- launch ----------------

extern "C" void kernel_launch(void* const* d_in, const int* in_sizes, int n_in,
                              void* d_out, int out_size, void* d_ws, size_t ws_size,
                              hipStream_t stream) {
    const float* x  = (const float*)d_in[0];
    const int*   ei = (const int*)d_in[1];
    const float* W1 = (const float*)d_in[2];
    const float* b1 = (const float*)d_in[3];
    const float* W2 = (const float*)d_in[4];
    const float* b2 = (const float*)d_in[5];
    const float* W3 = (const float*)d_in[6];
    const float* b3 = (const float*)d_in[7];
    float* out = (float*)d_out;

    int n = in_sizes[0] / F_IN;
    int e = in_sizes[1] / 2;
    const int* srcp = ei;
    const int* dstp = ei + e;

    size_t off = 0;
    auto alloc = [&](size_t bytes) -> char* {
        char* p = (char*)d_ws + off;
        off += (bytes + 255) & ~(size_t)255;
        return p;
    };
    int*   cnt      = (int*)alloc((size_t)n * 4);
    int*   cursor   = (int*)alloc((size_t)n * 4);
    int*   rowstart = (int*)alloc((size_t)(n + 1) * 4);
    int*   partial  = (int*)alloc(1024 * 4);
    int*   csr_src  = (int*)alloc((size_t)e * 4);
    float* csr_norm = (float*)alloc((size_t)e * 4);
    float* dinv     = (float*)alloc((size_t)n * 4);
    unsigned short* xb   = (unsigned short*)alloc((size_t)n * F_IN * 2);   // x bf16
    unsigned short* aggb = (unsigned short*)alloc((size_t)n * F_HID * 2);  // agg out bf16
    unsigned short* h1b  = (unsigned short*)alloc((size_t)n * F_HID * 2);  // h1 bf16
    unsigned short* W1t  = (unsigned short*)alloc((size_t)F_IN * F_HID * 2);
    unsigned short* W2t  = (unsigned short*)alloc((size_t)F_HID * F_HID * 2);
    float* h2  = (float*)alloc((size_t)n * F_HID * 4);
    float* hw3 = (float*)alloc((size_t)n * F_OUT * 4);

    const int TB = 256;
    hipMemsetAsync(cnt, 0, (size_t)n * 4, stream);
    hipMemsetAsync(cursor, 0, (size_t)n * 4, stream);

    count_kernel<<<(e + TB - 1) / TB, TB, 0, stream>>>(dstp, cnt, e);
    dinv_kernel<<<(n + TB - 1) / TB, TB, 0, stream>>>(cnt, dinv, n);
    int nb = (n + TB - 1) / TB;
    scan1_kernel<<<nb, TB, 0, stream>>>(cnt, rowstart, partial, n);
    scan2_kernel<<<1, TB, 0, stream>>>(partial, nb);
    scan3_kernel<<<nb, TB, 0, stream>>>(rowstart, partial, n, e);
    fill_kernel<<<(e + TB - 1) / TB, TB, 0, stream>>>(srcp, dstp, rowstart, cursor, dinv,
                                                      csr_src, csr_norm, e);

    // casts
    size_t xtotal = (size_t)n * F_IN;
    cast_kernel<<<(int)((xtotal / 4 + TB - 1) / TB), TB, 0, stream>>>(x, xb, xtotal);
    castT_kernel<<<(F_IN * F_HID + TB - 1) / TB, TB, 0, stream>>>(W1, W1t, F_IN, F_HID);
    castT_kernel<<<(F_HID * F_HID + TB - 1) / TB, TB, 0, stream>>>(W2, W2t, F_HID, F_HID);

    int nwave = (n + 3) / 4;
    dim3 gg((n + 63) / 64, F_HID / 64);

    // Layer 1: aggregate x_bf16 (128) -> aggb, MFMA GEMM+bias+relu -> h1 (bf16)
    agg_bf16_kernel<F_IN><<<nwave, 256, 0, stream>>>(xb, rowstart, csr_src, csr_norm, dinv,
                                                     aggb, n);
    gemm_mfma_kernel<F_IN, true, true><<<gg, 256, 0, stream>>>(aggb, W1t, b1, nullptr, h1b,
                                                               n, F_HID);

    // Layer 2: aggregate h1_bf16 (256) -> aggb, MFMA GEMM+bias+relu -> h2 (fp32)
    agg_bf16_kernel<F_HID><<<nwave, 256, 0, stream>>>(h1b, rowstart, csr_src, csr_norm, dinv,
                                                      aggb, n);
    gemm_mfma_kernel<F_HID, true, false><<<gg, 256, 0, stream>>>(aggb, W2t, b2, h2, nullptr,
                                                                 n, F_HID);

    // Layer 3: GEMM to 10-dim, aggregate 10-dim + bias + log_softmax
    gemm3_kernel<<<(n + TB - 1) / TB, TB, 0, stream>>>(h2, W3, hw3, n);
    final_kernel<<<(n + TB - 1) / TB, TB, 0, stream>>>(hw3, rowstart, csr_src, csr_norm, dinv,
                                                       b3, out, n);
}